// Round 2
// baseline (8474.873 us; speedup 1.0000x reference)
//
#include <hip/hip_runtime.h>

#define S_ 512
#define B_ 64
#define I_ 1024
#define H_ 1024
#define G_ 4096  // 4*H

typedef _Float16 f16x4 __attribute__((ext_vector_type(4)));
typedef _Float16 f16x8 __attribute__((ext_vector_type(8)));
typedef float f32x4 __attribute__((ext_vector_type(4)));

// ---------------- f32 -> f16 (plain) ----------------
__global__ __launch_bounds__(256) void cvt_f32_f16(const float* __restrict__ src,
                                                   _Float16* __restrict__ dst, int n) {
  const int stride = gridDim.x * blockDim.x * 4;
  for (long i = (long)(blockIdx.x * blockDim.x + threadIdx.x) * 4; i < n; i += stride) {
    const float4 v = *(const float4*)(src + i);
    f16x4 o;
    o.x = (_Float16)v.x;
    o.y = (_Float16)v.y;
    o.z = (_Float16)v.z;
    o.w = (_Float16)v.w;
    *(f16x4*)(dst + i) = o;
  }
}

// ---------------- f32 -> (f16 hi, f16 lo) split ----------------
__global__ __launch_bounds__(256) void cvt_split(const float* __restrict__ src,
                                                 _Float16* __restrict__ hi,
                                                 _Float16* __restrict__ lo, int n) {
  const int stride = gridDim.x * blockDim.x * 4;
  for (long i = (long)(blockIdx.x * blockDim.x + threadIdx.x) * 4; i < n; i += stride) {
    const float4 v = *(const float4*)(src + i);
    f16x4 h, l;
    h.x = (_Float16)v.x; l.x = (_Float16)(v.x - (float)h.x);
    h.y = (_Float16)v.y; l.y = (_Float16)(v.y - (float)h.y);
    h.z = (_Float16)v.z; l.z = (_Float16)(v.z - (float)h.z);
    h.w = (_Float16)v.w; l.w = (_Float16)(v.w - (float)h.w);
    *(f16x4*)(hi + i) = h;
    *(f16x4*)(lo + i) = l;
  }
}

// ---------------- async global->LDS helper (16B per lane) ----------------
__device__ __forceinline__ void gload16(const void* g, void* l) {
  __builtin_amdgcn_global_load_lds(
      (const __attribute__((address_space(1))) unsigned int*)g,
      (__attribute__((address_space(3))) unsigned int*)l, 16, 0, 0);
}

// ---------------- x_gates GEMM: C[M,N] = x[M,K](f32) * W[N,K]^T + (bx+bh) ----------------
// Split precision: x -> hi+lo in-register; W pre-split (hi,lo). 3 MFMA products.
// M=32768, N=4096, K=1024. 128x128 tile, BK=32, 4 waves (2x2 of 64x64).
template <typename XGT>
__global__ __launch_bounds__(256) void gemm_xg(const float* __restrict__ A,
                                               const _Float16* __restrict__ Bhi,
                                               const _Float16* __restrict__ Blo,
                                               const float* __restrict__ bx,
                                               const float* __restrict__ bh,
                                               XGT* __restrict__ C) {
  __shared__ __align__(16) float As[128 * 32];
  __shared__ __align__(16) _Float16 BsH[128 * 32];
  __shared__ __align__(16) _Float16 BsL[128 * 32];
  const int tileN = (blockIdx.x & 31) << 7;   // 32 N-tiles
  const int tileM = (blockIdx.x >> 5) << 7;   // 256 M-tiles
  const int w = threadIdx.x >> 6;
  const int lane = threadIdx.x & 63;
  const int wm = w & 1, wn = w >> 1;

  // A staging: 16 chunks of 8 rows x 32 f32 (1KB); wave w does chunks 4w..4w+3
  const int arow = lane >> 3;         // 0..7
  const int acol = (lane & 7) << 2;   // f32 col (4 floats = 16B)
  const float* ap0 = A + (long)(tileM + (4 * w + 0) * 8 + arow) * I_ + acol;
  const float* ap1 = A + (long)(tileM + (4 * w + 1) * 8 + arow) * I_ + acol;
  const float* ap2 = A + (long)(tileM + (4 * w + 2) * 8 + arow) * I_ + acol;
  const float* ap3 = A + (long)(tileM + (4 * w + 3) * 8 + arow) * I_ + acol;
  // B staging: 8 chunks of 16 rows x 32 f16 (1KB); wave w does chunks 2w, 2w+1
  const int brow = lane >> 2;         // 0..15
  const int bcol = (lane & 3) << 3;   // f16 col (8 halves = 16B)
  const _Float16* bh0 = Bhi + (long)(tileN + (2 * w + 0) * 16 + brow) * I_ + bcol;
  const _Float16* bh1 = Bhi + (long)(tileN + (2 * w + 1) * 16 + brow) * I_ + bcol;
  const _Float16* bl0 = Blo + (long)(tileN + (2 * w + 0) * 16 + brow) * I_ + bcol;
  const _Float16* bl1 = Blo + (long)(tileN + (2 * w + 1) * 16 + brow) * I_ + bcol;

  f32x4 acc[4][4] = {};
  const int fr = lane & 15;
  const int fk = (lane >> 4) << 3;

  for (int kk = 0; kk < I_; kk += 32) {
    gload16(ap0 + kk, &As[(4 * w + 0) * 256]);
    gload16(ap1 + kk, &As[(4 * w + 1) * 256]);
    gload16(ap2 + kk, &As[(4 * w + 2) * 256]);
    gload16(ap3 + kk, &As[(4 * w + 3) * 256]);
    gload16(bh0 + kk, &BsH[(2 * w + 0) * 512]);
    gload16(bh1 + kk, &BsH[(2 * w + 1) * 512]);
    gload16(bl0 + kk, &BsL[(2 * w + 0) * 512]);
    gload16(bl1 + kk, &BsL[(2 * w + 1) * 512]);
    __syncthreads();
    f16x8 ah[4], al[4], bhf[4], blf[4];
#pragma unroll
    for (int i = 0; i < 4; ++i) {
      const float* ap = &As[(wm * 64 + i * 16 + fr) * 32 + fk];
      const float4 v0 = *(const float4*)ap;
      const float4 v1 = *(const float4*)(ap + 4);
      float vv[8] = {v0.x, v0.y, v0.z, v0.w, v1.x, v1.y, v1.z, v1.w};
#pragma unroll
      for (int j = 0; j < 8; ++j) {
        const _Float16 hi = (_Float16)vv[j];
        ah[i][j] = hi;
        al[i][j] = (_Float16)(vv[j] - (float)hi);
      }
      bhf[i] = *(const f16x8*)&BsH[(wn * 64 + i * 16 + fr) * 32 + fk];
      blf[i] = *(const f16x8*)&BsL[(wn * 64 + i * 16 + fr) * 32 + fk];
    }
#pragma unroll
    for (int i = 0; i < 4; ++i)
#pragma unroll
      for (int j = 0; j < 4; ++j) {
        acc[i][j] = __builtin_amdgcn_mfma_f32_16x16x32_f16(ah[i], bhf[j], acc[i][j], 0, 0, 0);
        acc[i][j] = __builtin_amdgcn_mfma_f32_16x16x32_f16(al[i], bhf[j], acc[i][j], 0, 0, 0);
        acc[i][j] = __builtin_amdgcn_mfma_f32_16x16x32_f16(ah[i], blf[j], acc[i][j], 0, 0, 0);
      }
    __syncthreads();
  }

  // epilogue: C/D layout col=lane&15, row=(lane>>4)*4+r ; fuse bias (bx+bh)
#pragma unroll
  for (int j = 0; j < 4; ++j) {
    const int col = tileN + wn * 64 + j * 16 + fr;
    const float bias = bx[col] + bh[col];
#pragma unroll
    for (int i = 0; i < 4; ++i) {
      const int row0 = tileM + wm * 64 + i * 16 + ((lane >> 4) << 2);
#pragma unroll
      for (int r = 0; r < 4; ++r)
        C[(long)(row0 + r) * G_ + col] = (XGT)(acc[i][j][r] + bias);
    }
  }
}

// ---------------- one LSTM timestep (split-precision h) ----------------
// grid = 256 WGs: blockIdx = bg*64 + hs. Wave w = gate (i,f,g,o):
// gates[16b x 16h] = (h_hi + h_lo) @ Wh[gate rows]^T via 2 MFMA products.
template <int FIRST, typename XGT>
__global__ __launch_bounds__(256) void lstm_step(const XGT* __restrict__ xg,
                                                 const _Float16* __restrict__ Whh,
                                                 _Float16* __restrict__ h_hi,
                                                 _Float16* __restrict__ h_lo,
                                                 float* __restrict__ c_state,
                                                 float* __restrict__ out,
                                                 float* __restrict__ hT,
                                                 float* __restrict__ cT, int t) {
  __shared__ float gbuf[4][16][16];
  const int bg = blockIdx.x >> 6;
  const int hs = blockIdx.x & 63;
  const int w = threadIdx.x >> 6;
  const int lane = threadIdx.x & 63;

  if (!FIRST) {
    f32x4 acc0 = {}, acc1 = {};
    const long hoff = (long)(bg * 16 + (lane & 15)) * H_ + ((lane >> 4) << 3);
    const _Float16* hh = h_hi + hoff;
    const _Float16* hl = h_lo + hoff;
    const _Float16* wrow =
        Whh + (long)(w * H_ + hs * 16 + (lane & 15)) * H_ + ((lane >> 4) << 3);
#pragma unroll 4
    for (int kk = 0; kk < H_; kk += 64) {
      const f16x8 w0 = *(const f16x8*)(wrow + kk);
      const f16x8 w1 = *(const f16x8*)(wrow + kk + 32);
      acc0 = __builtin_amdgcn_mfma_f32_16x16x32_f16(*(const f16x8*)(hh + kk), w0, acc0, 0, 0, 0);
      acc0 = __builtin_amdgcn_mfma_f32_16x16x32_f16(*(const f16x8*)(hl + kk), w0, acc0, 0, 0, 0);
      acc1 = __builtin_amdgcn_mfma_f32_16x16x32_f16(*(const f16x8*)(hh + kk + 32), w1, acc1, 0, 0, 0);
      acc1 = __builtin_amdgcn_mfma_f32_16x16x32_f16(*(const f16x8*)(hl + kk + 32), w1, acc1, 0, 0, 0);
    }
#pragma unroll
    for (int r = 0; r < 4; ++r)
      gbuf[w][((lane >> 4) << 2) + r][lane & 15] = acc0[r] + acc1[r];
    __syncthreads();
  }

  const int tid = threadIdx.x;
  const int b = tid >> 4, j = tid & 15;
  const int gb = bg * 16 + b;
  const int gj = hs * 16 + j;
  const long xbase = ((long)t * B_ + gb) * G_ + gj;
  float gi = (float)xg[xbase];
  float gf = (float)xg[xbase + H_];
  float gg = (float)xg[xbase + 2 * H_];
  float go = (float)xg[xbase + 3 * H_];
  if (!FIRST) {
    gi += gbuf[0][b][j];
    gf += gbuf[1][b][j];
    gg += gbuf[2][b][j];
    go += gbuf[3][b][j];
  }
  const float iv = 1.f / (1.f + __expf(-gi));
  const float fv = 1.f / (1.f + __expf(-gf));
  const float gv = tanhf(gg);
  const float ov = 1.f / (1.f + __expf(-go));
  const float c_old = FIRST ? 0.f : c_state[gb * H_ + gj];
  const float cn = fv * c_old + iv * gv;
  const float hn = ov * tanhf(cn);
  c_state[gb * H_ + gj] = cn;
  const _Float16 hh16 = (_Float16)hn;
  h_hi[gb * H_ + gj] = hh16;
  h_lo[gb * H_ + gj] = (_Float16)(hn - (float)hh16);
  out[((long)gb * S_ + t) * H_ + gj] = hn;  // outputs [B,S,H]
  if (t == S_ - 1) {
    hT[gb * H_ + gj] = hn;
    cT[gb * H_ + gj] = cn;
  }
}

// ---------------- launch ----------------
extern "C" void kernel_launch(void* const* d_in, const int* in_sizes, int n_in,
                              void* d_out, int out_size, void* d_ws, size_t ws_size,
                              hipStream_t stream) {
  const float* x = (const float*)d_in[0];
  const float* Wx = (const float*)d_in[1];
  const float* bx = (const float*)d_in[2];
  const float* Wh = (const float*)d_in[3];
  const float* bh = (const float*)d_in[4];

  float* out = (float*)d_out;                    // [64][512][1024]
  float* hT = out + (long)B_ * S_ * H_;          // [64][1024]
  float* cT = hT + (long)B_ * H_;                // [64][1024]

  char* ws = (char*)d_ws;
  _Float16* Wxhi = (_Float16*)ws;                              // 8 MB
  _Float16* Wxlo = (_Float16*)(ws + (8l << 20));               // 8 MB
  _Float16* Whhi = (_Float16*)(ws + (16l << 20));              // 8 MB
  _Float16* h_hi = (_Float16*)(ws + (24l << 20));              // 128 KB
  _Float16* h_lo = (_Float16*)(ws + (24l << 20) + (128l << 10));  // 128 KB
  float* c_state = (float*)(ws + (24l << 20) + (256l << 10));     // 256 KB
  char* xg_raw = ws + (32l << 20);

  cvt_split<<<256, 256, 0, stream>>>(Wx, Wxhi, Wxlo, G_ * I_);
  cvt_f32_f16<<<256, 256, 0, stream>>>(Wh, Whhi, G_ * H_);

  const size_t needA = (32ll << 20) + (long long)S_ * B_ * G_ * 4;  // f32 x_gates
  const int nGemmBlk = (S_ * B_ / 128) * (G_ / 128);

  if (ws_size >= needA) {
    float* xg = (float*)xg_raw;
    gemm_xg<float><<<nGemmBlk, 256, 0, stream>>>(x, Wxhi, Wxlo, bx, bh, xg);
    lstm_step<1, float><<<256, 256, 0, stream>>>(xg, Whhi, h_hi, h_lo, c_state, out, hT, cT, 0);
    for (int t = 1; t < S_; ++t)
      lstm_step<0, float><<<256, 256, 0, stream>>>(xg, Whhi, h_hi, h_lo, c_state, out, hT, cT, t);
  } else {
    _Float16* xg = (_Float16*)xg_raw;
    gemm_xg<_Float16><<<nGemmBlk, 256, 0, stream>>>(x, Wxhi, Wxlo, bx, bh, xg);
    lstm_step<1, _Float16><<<256, 256, 0, stream>>>(xg, Whhi, h_hi, h_lo, c_state, out, hT, cT, 0);
    for (int t = 1; t < S_; ++t)
      lstm_step<0, _Float16><<<256, 256, 0, stream>>>(xg, Whhi, h_hi, h_lo, c_state, out, hT, cT, t);
  }
}